// Round 1
// baseline (3279.170 us; speedup 1.0000x reference)
//
#include <hip/hip_runtime.h>
#include <hip/hip_bf16.h>

// LSTM: B=1024, SEQ=128, H=1024, NCLS=10, IN_DIM=1.
// Strategy: fp16 MFMA (16x16x32) for the recurrent GEMM, fp32 state/epilogue.
// 128 per-step kernel launches (graph-captured); weights prepacked fp16.

#define HDIM 1024
#define SEQ 128
#define NCLS 10
#define BATCH 1024

using half8  = __attribute__((ext_vector_type(8))) _Float16;
using floatx4 = __attribute__((ext_vector_type(4))) float;

#define GLOBAL_AS const __attribute__((address_space(1))) void*
#define LDS_AS __attribute__((address_space(3))) void*

// ---------------------------------------------------------------------------
// Prepack: concat [w_gh; w_ih; w_fh; w_oh] rows into per-WG-contiguous fp16.
// Packed row p = u*128 + n, u in [0,32), n in [0,128): gate = n>>5,
// unit j = u*32 + (n&31). Source row = w_{gate}h[j][0..1023].
// ---------------------------------------------------------------------------
__global__ void prepack_kernel(const float* __restrict__ wgh,
                               const float* __restrict__ wih,
                               const float* __restrict__ wfh,
                               const float* __restrict__ woh,
                               _Float16* __restrict__ Wp) {
    int p = blockIdx.x;                 // 0..4095
    int u = p >> 7, n = p & 127;
    int gate = n >> 5;
    int j = u * 32 + (n & 31);
    const float* src;
    if (gate == 0) src = wgh; else if (gate == 1) src = wih;
    else if (gate == 2) src = wfh; else src = woh;
    src += (size_t)j * HDIM;
    int k = threadIdx.x * 4;            // 256 threads * 4 = 1024
    float4 v = *(const float4*)(src + k);
    union { _Float16 h[4]; uint2 u2; } cv;
    cv.h[0] = (_Float16)v.x; cv.h[1] = (_Float16)v.y;
    cv.h[2] = (_Float16)v.z; cv.h[3] = (_Float16)v.w;
    *(uint2*)(Wp + (size_t)p * HDIM + k) = cv.u2;
}

// ---------------------------------------------------------------------------
// One LSTM step. Grid 256 WGs x 256 threads (4 waves).
// WG tile: 128 batch rows x 128 gate-cols (= 4 gates x 32 units).
// Wave w: rows w*32..w*32+31 (2 m-tiles) x all 128 cols (8 n-tiles).
// LDS tiles 128x64 fp16, XOR-swizzled via global-side addressing so that
// global_load_lds (dest = base + lane*16) produces layout:
//   element (row, kb) lives at row*64 + ((kb ^ (row&7))*8) halves.
// ---------------------------------------------------------------------------
__global__ __launch_bounds__(256) void lstm_step(
    const _Float16* __restrict__ h_in, _Float16* __restrict__ h_out,
    float* __restrict__ c_state, const _Float16* __restrict__ Wp,
    const float* __restrict__ x, int t,
    const float* __restrict__ wgx, const float* __restrict__ wix,
    const float* __restrict__ wfx, const float* __restrict__ wox,
    const float* __restrict__ bg, const float* __restrict__ bi,
    const float* __restrict__ bf, const float* __restrict__ bo)
{
    __shared__ _Float16 lA[128 * 64];   // 16 KB
    __shared__ _Float16 lB[128 * 64];   // 16 KB
    __shared__ float lxt[128];

    const int blk = blockIdx.x;
    // XCD swizzle: round-robin dispatch (i%8) puts u-tiles {4x..4x+3} on XCD x
    const int u  = (blk & 7) * 4 + ((blk >> 3) & 3);  // unit-tile 0..31
    const int bc = blk >> 5;                           // batch chunk 0..7
    const int b0 = bc * 128;

    const int tid = threadIdx.x;
    const int wv = tid >> 6;
    const int l  = tid & 63;

    if (tid < 128) lxt[tid] = x[(size_t)(b0 + tid) * SEQ + t];

    floatx4 acc[2][8] = {};

    const _Float16* Abase = h_in + (size_t)b0 * HDIM;
    const _Float16* Bbase = Wp + (size_t)u * 128 * HDIM;

    // staging lane decomposition
    const int rl   = l >> 3;        // 0..7: row within 8-row group
    const int kbsw = l & 7;         // swizzled kb slot
    const int kb   = kbsw ^ rl;     // global kb fetched (row&7 == rl)

    const int lane15 = l & 15;
    const int quad   = l >> 4;
    const int rf     = lane15 & 7;  // row&7 for all fragment rows

    for (int kt = 0; kt < 16; ++kt) {
        const int k0 = kt * 64;
        __syncthreads();
        #pragma unroll
        for (int cq = 0; cq < 4; ++cq) {
            int q = wv * 4 + cq;            // 0..15: 8-row group
            int row = q * 8 + rl;
            __builtin_amdgcn_global_load_lds(
                (GLOBAL_AS)(Abase + (size_t)row * HDIM + k0 + kb * 8),
                (LDS_AS)(lA + q * 512 + l * 8), 16, 0, 0);
            __builtin_amdgcn_global_load_lds(
                (GLOBAL_AS)(Bbase + (size_t)row * HDIM + k0 + kb * 8),
                (LDS_AS)(lB + q * 512 + l * 8), 16, 0, 0);
        }
        __syncthreads();

        #pragma unroll
        for (int kc = 0; kc < 2; ++kc) {
            const int kbb = kc * 4 + quad;
            half8 afr[2], bfr[8];
            #pragma unroll
            for (int mi = 0; mi < 2; ++mi) {
                int row = wv * 32 + mi * 16 + lane15;
                afr[mi] = *(const half8*)(lA + row * 64 + ((kbb ^ rf) * 8));
            }
            #pragma unroll
            for (int ni = 0; ni < 8; ++ni) {
                int row = ni * 16 + lane15;
                bfr[ni] = *(const half8*)(lB + row * 64 + ((kbb ^ rf) * 8));
            }
            #pragma unroll
            for (int mi = 0; mi < 2; ++mi)
                #pragma unroll
                for (int ni = 0; ni < 8; ++ni)
                    acc[mi][ni] = __builtin_amdgcn_mfma_f32_16x16x32_f16(
                        afr[mi], bfr[ni], acc[mi][ni], 0, 0, 0);
        }
    }

    // Epilogue: C/D layout col=lane&15, row=quad*4+reg. Lane holds all 4
    // gates for its (batch row, unit): gate g at n-tile 2g+p.
    #pragma unroll
    for (int p = 0; p < 2; ++p) {
        const int j = u * 32 + p * 16 + lane15;   // global unit
        const float wg_ = wgx[j], wi_ = wix[j], wf_ = wfx[j], wo_ = wox[j];
        const float bg_ = bg[j], bi_ = bi[j], bf_ = bf[j], bo_ = bo[j];
        #pragma unroll
        for (int mi = 0; mi < 2; ++mi) {
            #pragma unroll
            for (int r = 0; r < 4; ++r) {
                const int m = wv * 32 + mi * 16 + quad * 4 + r;
                const float xt = lxt[m];
                const size_t idx = (size_t)(b0 + m) * HDIM + j;
                float pg = acc[mi][0 + p][r] + xt * wg_ + bg_;
                float pi = acc[mi][2 + p][r] + xt * wi_ + bi_;
                float pf = acc[mi][4 + p][r] + xt * wf_ + bf_;
                float po = acc[mi][6 + p][r] + xt * wo_ + bo_;
                float g  = tanhf(pg);
                float ii = 1.f / (1.f + __expf(-pi));
                float ff = 1.f / (1.f + __expf(-pf));
                float oo = 1.f / (1.f + __expf(-po));
                float cn = g * ii + c_state[idx] * ff;
                c_state[idx] = cn;
                h_out[idx] = (_Float16)(tanhf(cn) * oo);
            }
        }
    }
}

// ---------------------------------------------------------------------------
// logits = h_last @ w_ph^T + bias_p. One wave per batch row.
// ---------------------------------------------------------------------------
__global__ void logits_kernel(const _Float16* __restrict__ h,
                              const float* __restrict__ wph,
                              const float* __restrict__ bp,
                              float* __restrict__ out) {
    const int wave = (blockIdx.x * blockDim.x + threadIdx.x) >> 6; // 0..1023
    const int l = threadIdx.x & 63;
    float acc[NCLS];
    #pragma unroll
    for (int c = 0; c < NCLS; ++c) acc[c] = 0.f;
    for (int k = l; k < HDIM; k += 64) {
        float hv = (float)h[(size_t)wave * HDIM + k];
        #pragma unroll
        for (int c = 0; c < NCLS; ++c)
            acc[c] += hv * wph[c * HDIM + k];
    }
    #pragma unroll
    for (int c = 0; c < NCLS; ++c) {
        float v = acc[c];
        #pragma unroll
        for (int off = 32; off > 0; off >>= 1)
            v += __shfl_down(v, off, 64);
        if (l == 0) out[wave * NCLS + c] = v + bp[c];
    }
}

extern "C" void kernel_launch(void* const* d_in, const int* in_sizes, int n_in,
                              void* d_out, int out_size, void* d_ws, size_t ws_size,
                              hipStream_t stream) {
    const float* x   = (const float*)d_in[0];
    const float* wgx = (const float*)d_in[1];
    const float* wgh = (const float*)d_in[2];
    const float* wix = (const float*)d_in[3];
    const float* wih = (const float*)d_in[4];
    const float* wfx = (const float*)d_in[5];
    const float* wfh = (const float*)d_in[6];
    const float* wox = (const float*)d_in[7];
    const float* woh = (const float*)d_in[8];
    const float* wph = (const float*)d_in[9];
    const float* bg  = (const float*)d_in[10];
    const float* bi  = (const float*)d_in[11];
    const float* bf  = (const float*)d_in[12];
    const float* bo  = (const float*)d_in[13];
    const float* bp  = (const float*)d_in[14];
    float* out = (float*)d_out;

    char* ws = (char*)d_ws;
    _Float16* Wp     = (_Float16*)(ws);                      // 8 MB
    float*    cstate = (float*)(ws + (8u << 20));            // 4 MB
    _Float16* hbuf0  = (_Float16*)(ws + (12u << 20));        // 2 MB
    _Float16* hbuf1  = (_Float16*)(ws + (14u << 20));        // 2 MB

    // ws is poisoned 0xAA before every timed call: zero the state each call.
    hipMemsetAsync(cstate, 0, 4u << 20, stream);
    hipMemsetAsync(hbuf0, 0, 2u << 20, stream);

    prepack_kernel<<<4096, 256, 0, stream>>>(wgh, wih, wfh, woh, Wp);

    _Float16* hin = hbuf0;
    _Float16* hout = hbuf1;
    for (int t = 0; t < SEQ; ++t) {
        lstm_step<<<256, 256, 0, stream>>>(hin, hout, cstate, Wp, x, t,
                                           wgx, wix, wfx, wox, bg, bi, bf, bo);
        _Float16* tmp = hin; hin = hout; hout = tmp;
    }
    logits_kernel<<<256, 256, 0, stream>>>(hin, wph, bp, out);
}